// Round 9
// baseline (6107.238 us; speedup 1.0000x reference)
//
#include <hip/hip_runtime.h>
#include <hip/hip_bf16.h>
#include <math.h>

using bf16 = __hip_bfloat16;

typedef __attribute__((ext_vector_type(8))) short short8;
typedef __attribute__((ext_vector_type(4))) short shortx4;
typedef __attribute__((ext_vector_type(4))) float floatx4;

#define D_MODEL 1024
#define D_STATE 16
#define D_FFN   4096
#define D_INNER 2048
#define DT_RANK 64
#define BSZ     2
#define SEQ     2048
#define MROWS   (BSZ*SEQ)   /* 4096 */
#define NCHUNK  16
#define CLEN    (SEQ/NCHUNK)   /* 128 */

static __device__ __forceinline__ float bf2f(bf16 v) { return __bfloat162float(v); }
static __device__ __forceinline__ short f2s(float f) {
    bf16 h = __float2bfloat16(f);
    return *reinterpret_cast<short*>(&h);
}
static __device__ __forceinline__ float sbf(short s) {
    union { short s; bf16 h; } u; u.s = s; return __bfloat162float(u.h);
}
static __device__ __forceinline__ float rd(const bf16* p)  { return bf2f(*p); }
static __device__ __forceinline__ float rd(const float* p) { return *p; }
static __device__ __forceinline__ void  wr(bf16* p, float v)  { *p = __float2bfloat16(v); }
static __device__ __forceinline__ void  wr(float* p, float v) { *p = v; }

// s_waitcnt immediate (gfx9 enc): lgkmcnt(0) only — vmcnt/expcnt no-wait.
#define WAIT_LGKM0 0xC07F

// ---------------------------------------------------------------------------
// GEMM: C[M,N] = act(A[M,K] @ W[N,K]^T + bias) (+ resid). bf16 in, f32 accum.
// Pipelined K-loop (BK=32): register staging with prefetch distance 2,
// raw s_barrier (no vmcnt drain), swizzled LDS (bank-conflict-free).
// Tile = (IT*32) x (JT*32), 4 waves in 2x2, wave tile (IT*16)x(JT*16).
// Epilogue: chunked LDS transpose (f32, padded) -> coalesced stores.
// Optional second (W2,C2) for by >= mtiles; XCD band swizzle when gx%8==0.
// ---------------------------------------------------------------------------
#define BK 32

enum { ACT_NONE = 0, ACT_GELU = 1, ACT_SOFTPLUS = 2 };

template<int IT, int JT, int ACT, bool HAS_BIAS, bool HAS_RES,
         typename TR, typename TC>
__global__ __launch_bounds__(256)
void gemm_bt(const bf16* __restrict__ A, int lda,
             const bf16* __restrict__ W, int ldw,
             TC* __restrict__ C, int ldc,
             const float* __restrict__ bias,
             const TR* __restrict__ resid, int ldr,
             int K,
             const bf16* __restrict__ W2, TC* __restrict__ C2, int mtiles)
{
    constexpr int BM = IT * 32, BN = JT * 32;
    constexpr int NGA = BM / 64;            // A 16-row groups staged per wave
    constexpr int NGB = BN / 64;
    constexpr int ABYTES = BM * BK * 2;
    constexpr int BBYTES = BN * BK * 2;
    constexpr int EBYTES = 16 * (BN + 4) * 4;
    constexpr int SBYTES = (ABYTES + BBYTES) > EBYTES ? (ABYTES + BBYTES) : EBYTES;

    __shared__ __align__(16) char smem[SBYTES];
    bf16*  As = (bf16*)smem;
    bf16*  Bs = (bf16*)(smem + ABYTES);
    float* Ct = (float*)smem;               // epilogue alias (after K-loop)

    const int tid  = threadIdx.x;
    const int lane = tid & 63;
    const int wid  = tid >> 6;
    const int wm   = wid >> 1;
    const int wn   = wid & 1;
    const int quad = lane >> 4;
    const int lrow = lane & 15;

    // XCD band swizzle (bijective; gx multiple of 8)
    int bx = blockIdx.x, by = blockIdx.y;
    const int gx = gridDim.x;
    if ((gx & 7) == 0) {
        int id = by * gx + bx;
        int bw = gx >> 3;
        int band = id & 7, s = id >> 3;
        bx = band * bw + (s % bw);
        by = s / bw;
    }
    if (by >= mtiles) { by -= mtiles; W = W2; C = C2; }

    const long m0 = (long)by * BM;
    const long n0 = (long)bx * BN;

    // register staging addresses
    const int rlg  = lane >> 2;                 // row within 16-row group
    const int kfo  = (lane & 3) * 8;            // coalesced col offset
    const int slot = (((lane & 3) ^ ((rlg >> 1) & 3))) * 8;   // swizzled LDS col

    const bf16* Ag[NGA]; int soA[NGA];
    const bf16* Wg[NGB]; int soB[NGB];
    #pragma unroll
    for (int g = 0; g < NGA; ++g) {
        const int grp = wid * NGA + g;
        Ag[g]  = A + (m0 + grp * 16 + rlg) * (long)lda + kfo;
        soA[g] = (grp * 16 + rlg) * 32 + slot;
    }
    #pragma unroll
    for (int g = 0; g < NGB; ++g) {
        const int grp = wid * NGB + g;
        Wg[g]  = W + (n0 + grp * 16 + rlg) * (long)ldw + kfo;
        soB[g] = (grp * 16 + rlg) * 32 + slot;
    }

    // fragment read col offset (matches store swizzle; 2-way banks = free)
    const int co = ((quad ^ ((lrow >> 1) & 3))) * 8;

    floatx4 acc[IT][JT] = {};

    // prologue: tiles 0,1 -> register sets
    short8 ra[2][NGA], rb[2][NGB];
    #pragma unroll
    for (int g = 0; g < NGA; ++g) ra[0][g] = *(const short8*)Ag[g];
    #pragma unroll
    for (int g = 0; g < NGB; ++g) rb[0][g] = *(const short8*)Wg[g];
    const int nit = K / BK;
    if (nit > 1) {
        #pragma unroll
        for (int g = 0; g < NGA; ++g) ra[1][g] = *(const short8*)(Ag[g] + BK);
        #pragma unroll
        for (int g = 0; g < NGB; ++g) rb[1][g] = *(const short8*)(Wg[g] + BK);
    }

    for (int it = 0; it < nit; ++it) {
        const int s = it & 1;
        #pragma unroll
        for (int g = 0; g < NGA; ++g) *(short8*)(As + soA[g]) = ra[s][g];
        #pragma unroll
        for (int g = 0; g < NGB; ++g) *(short8*)(Bs + soB[g]) = rb[s][g];
        __builtin_amdgcn_s_waitcnt(WAIT_LGKM0);   // my ds_writes visible
        __builtin_amdgcn_s_barrier();             // all writes visible (no vm drain)

        if (it + 2 < nit) {                       // distance-2 prefetch
            const long ko = (long)(it + 2) * BK;
            #pragma unroll
            for (int g = 0; g < NGA; ++g) ra[s][g] = *(const short8*)(Ag[g] + ko);
            #pragma unroll
            for (int g = 0; g < NGB; ++g) rb[s][g] = *(const short8*)(Wg[g] + ko);
        }

        short8 af[IT], bfv[JT];
        #pragma unroll
        for (int i = 0; i < IT; i++)
            af[i] = *(const short8*)(As + (wm * IT * 16 + i * 16 + lrow) * 32 + co);
        #pragma unroll
        for (int j = 0; j < JT; j++)
            bfv[j] = *(const short8*)(Bs + (wn * JT * 16 + j * 16 + lrow) * 32 + co);
        #pragma unroll
        for (int i = 0; i < IT; i++)
            #pragma unroll
            for (int j = 0; j < JT; j++)
                acc[i][j] = __builtin_amdgcn_mfma_f32_16x16x32_bf16(af[i], bfv[j], acc[i][j], 0, 0, 0);

        __builtin_amdgcn_s_barrier();             // reads done before overwrite
    }

    // ---------------- epilogue ----------------
    // bias + activation in-register (C/D layout: row=quad*4+r, col=lrow)
    if (HAS_BIAS || ACT != ACT_NONE) {
        #pragma unroll
        for (int j = 0; j < JT; ++j) {
            const long col = n0 + wn * JT * 16 + j * 16 + lrow;
            const float bv = HAS_BIAS ? bias[col] : 0.0f;
            #pragma unroll
            for (int i = 0; i < IT; ++i)
                #pragma unroll
                for (int r = 0; r < 4; ++r) {
                    float v = acc[i][j][r] + bv;
                    if (ACT == ACT_GELU)     v = 0.5f * v * (1.0f + erff(v * 0.70710678118f));
                    if (ACT == ACT_SOFTPLUS) v = (v > 20.0f) ? v : log1pf(__expf(v));
                    acc[i][j][r] = v;
                }
        }
    }

    // chunked LDS transpose: 16 rows/chunk, padded f32 LDS, coalesced stores
    constexpr int LDCT = BN + 4;
    #pragma unroll
    for (int c = 0; c < BM / 16; ++c) {
        __builtin_amdgcn_s_barrier();
        #pragma unroll
        for (int i = 0; i < IT; ++i) {
            if (wm * IT + i == c) {
                #pragma unroll
                for (int j = 0; j < JT; ++j) {
                    const int cl = wn * JT * 16 + j * 16 + lrow;
                    #pragma unroll
                    for (int r = 0; r < 4; ++r)
                        Ct[(quad * 4 + r) * LDCT + cl] = acc[i][j][r];
                }
            }
        }
        __builtin_amdgcn_s_waitcnt(WAIT_LGKM0);
        __builtin_amdgcn_s_barrier();
        const long rowg0 = m0 + c * 16;
        #pragma unroll
        for (int p = 0; p < (16 * BN) / (256 * 4); ++p) {
            const int g   = p * 256 + tid;
            const int row = (g * 4) / BN;
            const int col = (g * 4) & (BN - 1);
            const long rowg = rowg0 + row;
            float4 v4 = *(const float4*)(Ct + row * LDCT + col);
            float vv[4] = { v4.x, v4.y, v4.z, v4.w };
            #pragma unroll
            for (int e = 0; e < 4; ++e) {
                float v = vv[e];
                if (HAS_RES) v += rd(resid + rowg * (long)ldr + n0 + col + e);
                wr(C + rowg * (long)ldc + n0 + col + e, v);
            }
        }
    }
}

// ---------------------------------------------------------------------------
// fused weight/input prep (f32 -> bf16), 8 elems/thread
// ---------------------------------------------------------------------------
static __device__ __forceinline__ void cvt8(const float* __restrict__ s,
                                            bf16* __restrict__ d, long i)
{
    float4 a = *((const float4*)s + i * 2);
    float4 b = *((const float4*)s + i * 2 + 1);
    short8 r;
    r[0] = f2s(a.x); r[1] = f2s(a.y); r[2] = f2s(a.z); r[3] = f2s(a.w);
    r[4] = f2s(b.x); r[5] = f2s(b.y); r[6] = f2s(b.z); r[7] = f2s(b.w);
    *(short8*)(d + i * 8) = r;
}

__global__ __launch_bounds__(256)
void prep1(const float* __restrict__ x, const float* __restrict__ inw,
           const float* __restrict__ dtw, const float* __restrict__ xprojw,
           bf16* __restrict__ xbf, bf16* __restrict__ inwb,
           bf16* __restrict__ dtwb, bf16* __restrict__ wpad)
{
    const int bid = blockIdx.x;
    const long t = threadIdx.x;
    if (bid < 2048)      cvt8(x,   xbf,  (long)bid * 256 + t);
    else if (bid < 4096) cvt8(inw, inwb, (long)(bid - 2048) * 256 + t);
    else if (bid < 4160) cvt8(dtw, dtwb, (long)(bid - 4096) * 256 + t);
    else {
        long i = (long)(bid - 4160) * 256 + t;   // 8-elem groups of wpad (128x2048)
        int row = (int)(i >> 8);
        int c8  = (int)(i & 255) * 8;
        short8 r = {0, 0, 0, 0, 0, 0, 0, 0};
        if (row < 96) {
            const float* s = xprojw + (long)row * 2048 + c8;
            float4 a = *(const float4*)s, b = *(const float4*)(s + 4);
            r[0] = f2s(a.x); r[1] = f2s(a.y); r[2] = f2s(a.z); r[3] = f2s(a.w);
            r[4] = f2s(b.x); r[5] = f2s(b.y); r[6] = f2s(b.z); r[7] = f2s(b.w);
        }
        *(short8*)(wpad + (long)row * 2048 + c8) = r;
    }
}

__global__ __launch_bounds__(256)
void prep2(const float* __restrict__ outw, const float* __restrict__ w1,
           const float* __restrict__ w2,
           bf16* __restrict__ outwb, bf16* __restrict__ w1b,
           bf16* __restrict__ w2b)
{
    const int bid = blockIdx.x;
    const long t = threadIdx.x;
    if (bid < 1024)      cvt8(outw, outwb, (long)bid * 256 + t);
    else if (bid < 3072) cvt8(w1, w1b, (long)(bid - 1024) * 256 + t);
    else                 cvt8(w2, w2b, (long)(bid - 3072) * 256 + t);
}

// ---------------------------------------------------------------------------
// depthwise causal conv (K=3) + bias + silu
// ---------------------------------------------------------------------------
__global__ __launch_bounds__(256)
void conv_silu(const bf16* __restrict__ xpre, const float* __restrict__ cw,
               const float* __restrict__ cb, bf16* __restrict__ xp)
{
    long i = (long)blockIdx.x * 256 + threadIdx.x;
    int  d  = (int)(i & (D_INNER - 1));
    long bl = i >> 11;
    long l  = bl & (SEQ - 1);

    float w0 = cw[d * 3 + 0];
    float w1 = cw[d * 3 + 1];
    float w2 = cw[d * 3 + 2];
    float acc = cb[d] + w2 * bf2f(xpre[i]);
    if (l >= 1) acc += w1 * bf2f(xpre[i - D_INNER]);
    if (l >= 2) acc += w0 * bf2f(xpre[i - 2 * D_INNER]);
    float s = acc / (1.0f + __expf(-acc));
    xp[i] = __float2bfloat16(s);
}

// ---------------------------------------------------------------------------
// Chunked SSM scan (verified rounds 4-8)
// ---------------------------------------------------------------------------
#define SROWS 16
#define SDB   64
#define SNB   (CLEN/SROWS)   /* 8 */

__global__ __launch_bounds__(256)
void scan_part(const bf16* __restrict__ dt, const bf16* __restrict__ xp,
               const bf16* __restrict__ dbc, const float* __restrict__ Alog,
               float* __restrict__ Pbuf, float* __restrict__ Qbuf)
{
    __shared__ float2 Ap[2][SROWS][SDB];   // (dt, dt*xp)
    __shared__ float  Bp[2][SROWS][16];

    const int tid  = threadIdx.x;
    const int c    = blockIdx.x & (NCHUNK - 1);
    const int dgrp = (blockIdx.x >> 4) & 31;
    const int b    = blockIdx.x >> 9;
    const int d0   = dgrp * SDB;
    const long row0 = (long)b * SEQ + (long)c * CLEN;

    const int sl  = tid >> 4;
    const int sq  = tid & 15;
    const int sd4 = sq * 4;

    const int nt = tid & 3;
    const int dl = tid >> 2;
    const int n0 = nt * 4;
    const int d  = d0 + dl;

    const float4 Av = *(const float4*)(Alog + d * 16 + n0);
    float Ad[4] = { -__expf(Av.x), -__expf(Av.y), -__expf(Av.z), -__expf(Av.w) };

    float rdt[4], rdx[4], rB;
    auto ldb = [&](int bb) {
        long row = row0 + bb * SROWS + sl;
        shortx4 dv = *(const shortx4*)(dt + row * D_INNER + d0 + sd4);
        shortx4 xv = *(const shortx4*)(xp + row * D_INNER + d0 + sd4);
        #pragma unroll
        for (int k = 0; k < 4; k++) {
            float f = sbf(dv[k]);
            rdt[k] = f;
            rdx[k] = f * sbf(xv[k]);
        }
        rB = bf2f(dbc[row * 128 + 64 + sq]);
    };
    auto stb = [&](int bb) {
        int s = bb & 1;
        #pragma unroll
        for (int k = 0; k < 4; k++)
            Ap[s][sl][sd4 + k] = make_float2(rdt[k], rdx[k]);
        Bp[s][sl][sq] = rB;
    };

    float h[4] = {0.f, 0.f, 0.f, 0.f};
    float sdt = 0.f;

    ldb(0); stb(0);
    for (int bb = 0; bb < SNB; bb++) {
        if (bb + 1 < SNB) ldb(bb + 1);
        __syncthreads();
        const int s = bb & 1;
        #pragma unroll
        for (int l = 0; l < SROWS; l++) {
            float2  a  = Ap[s][l][dl];
            floatx4 Bq = *(const floatx4*)&Bp[s][l][n0];
            sdt += a.x;
            #pragma unroll
            for (int k = 0; k < 4; k++)
                h[k] = __expf(a.x * Ad[k]) * h[k] + a.y * Bq[k];
        }
        if (bb + 1 < SNB) stb(bb + 1);
    }

    const long base = ((long)(b * NCHUNK + c) * D_INNER + d) * 16 + n0;
    floatx4 P = { __expf(Ad[0] * sdt), __expf(Ad[1] * sdt),
                  __expf(Ad[2] * sdt), __expf(Ad[3] * sdt) };
    floatx4 Q = { h[0], h[1], h[2], h[3] };
    *(floatx4*)(Pbuf + base) = P;
    *(floatx4*)(Qbuf + base) = Q;
}

__global__ __launch_bounds__(256)
void scan_combine(const float* __restrict__ Pbuf, float* __restrict__ Qbuf,
                  float* __restrict__ state)
{
    long i = (long)blockIdx.x * 256 + threadIdx.x;   // 65536 = (b,d,n)
    int  n = (int)(i & 15);
    int  d = (int)((i >> 4) & (D_INNER - 1));
    int  b = (int)(i >> 15);
    float h = 0.0f;
    #pragma unroll
    for (int c = 0; c < NCHUNK; c++) {
        const long idx = ((long)(b * NCHUNK + c) * D_INNER + d) * 16 + n;
        float P = Pbuf[idx], Q = Qbuf[idx];
        Qbuf[idx] = h;               // exclusive prefix = h_in for chunk c
        h = P * h + Q;
    }
    state[((long)b * D_INNER + d) * 16 + n] = h;
}

__global__ __launch_bounds__(256)
void scan_final(const bf16* __restrict__ dt, bf16* __restrict__ xp,
                const bf16* __restrict__ dbc, const float* __restrict__ Alog,
                const bf16* __restrict__ z, const float* __restrict__ Dp,
                const float* __restrict__ Qbuf)
{
    __shared__ float2 Ap [2][SROWS][SDB];   // (dt, dt*xp)
    __shared__ float2 BCp[2][SROWS][16];    // (B, C)
    __shared__ float2 GWp[2][SROWS][SDB];   // (g=silu(z), w=xp*Dp*g)

    const int tid  = threadIdx.x;
    const int c    = blockIdx.x & (NCHUNK - 1);
    const int dgrp = (blockIdx.x >> 4) & 31;
    const int b    = blockIdx.x >> 9;
    const int d0   = dgrp * SDB;
    const long row0 = (long)b * SEQ + (long)c * CLEN;

    const int sl  = tid >> 4;
    const int sq  = tid & 15;
    const int sd4 = sq * 4;

    const int nt = tid & 3;
    const int dl = tid >> 2;
    const int n0 = nt * 4;
    const int d  = d0 + dl;

    const float4 Av = *(const float4*)(Alog + d * 16 + n0);
    float Ad[4] = { -__expf(Av.x), -__expf(Av.y), -__expf(Av.z), -__expf(Av.w) };
    const float4 Dv = *(const float4*)(Dp + d0 + sd4);
    const float Dk[4] = { Dv.x, Dv.y, Dv.z, Dv.w };

    float rdt[4], rdx[4], rg[4], rw[4], rB, rC;
    auto ldb = [&](int bb) {
        long row = row0 + bb * SROWS + sl;
        shortx4 dv = *(const shortx4*)(dt + row * D_INNER + d0 + sd4);
        shortx4 xv = *(const shortx4*)(xp + row * D_INNER + d0 + sd4);
        shortx4 zv = *(const shortx4*)(z  + row * D_INNER + d0 + sd4);
        #pragma unroll
        for (int k = 0; k < 4; k++) {
            float f  = sbf(dv[k]);
            float xf = sbf(xv[k]);
            float zf = sbf(zv[k]);
            float g  = zf / (1.0f + __expf(-zf));
            rdt[k] = f;
            rdx[k] = f * xf;
            rg[k]  = g;
            rw[k]  = xf * Dk[k] * g;
        }
        rB = bf2f(dbc[row * 128 + 64 + sq]);
        rC = bf2f(dbc[row * 128 + 80 + sq]);
    };
    auto stb = [&](int bb) {
        int s = bb & 1;
        #pragma unroll
        for (int k = 0; k < 4; k++) {
            Ap [s][sl][sd4 + k] = make_float2(rdt[k], rdx[k]);
            GWp[s][sl][sd4 + k] = make_float2(rg[k], rw[k]);
        }
        BCp[s][sl][sq] = make_float2(rB, rC);
    };

    float h[4];
    {
        const long base = ((long)(b * NCHUNK + c) * D_INNER + d) * 16 + n0;
        floatx4 q = *(const floatx4*)(Qbuf + base);
        h[0] = q[0]; h[1] = q[1]; h[2] = q[2]; h[3] = q[3];
    }

    ldb(0); stb(0);
    for (int bb = 0; bb < SNB; bb++) {
        if (bb + 1 < SNB) ldb(bb + 1);
        __syncthreads();
        const int s = bb & 1;
        #pragma unroll
        for (int l = 0; l < SROWS; l++) {
            float2  a   = Ap[s][l][dl];
            floatx4 bc0 = *(const floatx4*)&BCp[s][l][n0];      // B0,C0,B1,C1
            floatx4 bc1 = *(const floatx4*)&BCp[s][l][n0 + 2];  // B2,C2,B3,C3
            float yv;
            h[0] = __expf(a.x * Ad[0]) * h[0] + a.y * bc0[0];
            yv   = h[0] * bc0[1];
            h[1] = __expf(a.x * Ad[1]) * h[1] + a.y * bc0[2];
            yv  += h[1] * bc0[3];
            h[2] = __expf(a.x * Ad[2]) * h[2] + a.y * bc1[0];
            yv  += h[2] * bc1[1];
            h[3] = __expf(a.x * Ad[3]) * h[3] + a.y * bc1[2];
            yv  += h[3] * bc1[3];
            yv += __shfl_xor(yv, 1);
            yv += __shfl_xor(yv, 2);
            if (nt == 0) {
                float2 gw = GWp[s][l][dl];
                float out = yv * gw.x + gw.y;
                xp[(row0 + bb * SROWS + l) * (long)D_INNER + d0 + dl] =
                    __float2bfloat16(out);
            }
        }
        if (bb + 1 < SNB) stb(bb + 1);
    }
}

// ---------------------------------------------------------------------------
extern "C" void kernel_launch(void* const* d_in, const int* in_sizes, int n_in,
                              void* d_out, int out_size, void* d_ws, size_t ws_size,
                              hipStream_t stream)
{
    const float* x      = (const float*)d_in[0];
    const float* inw    = (const float*)d_in[1];
    const float* convw  = (const float*)d_in[2];
    const float* convb  = (const float*)d_in[3];
    const float* xprojw = (const float*)d_in[4];
    const float* dtw    = (const float*)d_in[5];
    const float* dtbias = (const float*)d_in[6];
    const float* Alog   = (const float*)d_in[7];
    const float* Dp     = (const float*)d_in[8];
    const float* outw   = (const float*)d_in[9];
    const float* w1     = (const float*)d_in[10];
    const float* b1     = (const float*)d_in[11];
    const float* w2     = (const float*)d_in[12];
    const float* b2     = (const float*)d_in[13];

    float* out0 = (float*)d_out;                     // (2,2048,1024) f32 @ [0,16MiB)
    float* out1 = out0 + (long)MROWS * D_MODEL;      // (2,2048,16)   f32 @ [16,16.25MiB)

    // ws (57.5 MiB, proven): 3 act bufs + dbc + wpad + W8 (inw -> w2)
    bf16* buf0 = (bf16*)d_ws;                        // xpre -> dt -> hidden lo
    bf16* buf1 = buf0 + (long)MROWS * D_INNER;       // xp -> gated y (in-place) -> hidden hi
    bf16* buf2 = buf1 + (long)MROWS * D_INNER;       // z -> x1
    bf16* dbc  = buf2 + (long)MROWS * D_INNER;       // (4096,128), 96 cols used
    bf16* wpad = dbc  + (long)MROWS * 128;           // (128,2048)
    bf16* W8   = wpad + 128 * 2048;                  // 8 MiB: inw (prep1) -> w2 (prep2)

    // d_out scratch overlays (each dead before its region is clobbered):
    bf16*  dtwb  = (bf16*)d_out;                               // [0,0.25M) prep1->dtGEMM; clobbered by Pbuf
    float* Pbuf  = (float*)d_out;                              // [0,4M)  scan
    float* Qbuf  = Pbuf + (long)BSZ * NCHUNK * D_INNER * 16;   // [4,8M)  scan
    bf16*  xbf   = (bf16*)((char*)d_out + 8 * 1024 * 1024);    // [8,16M) prep1->in_proj
    bf16*  w1b   = (bf16*)d_out;                               // [0,8M)  prep2->FFN1 (P/Q dead)
    bf16*  outwb = (bf16*)((char*)d_out + 8 * 1024 * 1024);    // [8,12M) prep2->out_proj (xbf dead)

    dim3 blk(256);
    const float* nf = nullptr;

    // prep1: x->xbf, inw->W8, dtw->dtwb, xprojw->wpad   (one dispatch)
    prep1<<<dim3(4288), blk, 0, stream>>>(x, inw, dtw, xprojw, xbf, W8, dtwb, wpad);

    // fused in_proj: xpre = x@inw_lo^T -> buf0 ; z = x@inw_hi^T -> buf2
    gemm_bt<4, 4, ACT_NONE, false, false, float, bf16>
        <<<dim3(16, 64), blk, 0, stream>>>(
        xbf, D_MODEL, W8, D_MODEL, buf0, D_INNER, nullptr, nf, 0, D_MODEL,
        W8 + (long)D_INNER * D_MODEL, buf2, 32);

    // xp = silu(causal_conv(xpre) + conv_b)
    conv_silu<<<dim3(32768), blk, 0, stream>>>(buf0, convw, convb, buf1);

    // dbc = xp @ x_proj_w^T              (4096 x 128pad, K=2048), BM=64 tile
    gemm_bt<2, 4, ACT_NONE, false, false, float, bf16>
        <<<dim3(1, 64), blk, 0, stream>>>(
        buf1, D_INNER, wpad, D_INNER, dbc, 128, nullptr, nf, 0, D_INNER,
        wpad, dbc, 1000);

    // dt = softplus(dbc[:, :64] @ dt_proj_w^T + dt_proj_b)   (4096 x 2048, K=64)
    gemm_bt<4, 4, ACT_SOFTPLUS, true, false, float, bf16>
        <<<dim3(16, 32), blk, 0, stream>>>(
        dbc, 128, dtwb, DT_RANK, buf0, D_INNER, dtbias, nf, 0, DT_RANK,
        dtwb, buf0, 1000);

    // chunked scan: phase1 -> combine (writes state) -> phase3 (gated y in buf1)
    scan_part<<<dim3(BSZ * NCHUNK * (D_INNER / SDB)), blk, 0, stream>>>(
        buf0, buf1, dbc, Alog, Pbuf, Qbuf);
    scan_combine<<<dim3(256), blk, 0, stream>>>(Pbuf, Qbuf, out1);
    scan_final<<<dim3(BSZ * NCHUNK * (D_INNER / SDB)), blk, 0, stream>>>(
        buf0, buf1, dbc, Alog, buf2, Dp, Qbuf);

    // prep2: outw->outwb, w1->w1b, w2->W8   (one dispatch; P/Q + xbf dead)
    prep2<<<dim3(5120), blk, 0, stream>>>(outw, w1, w2, outwb, w1b, W8);

    // x1 = x + y @ out_proj_w^T          (4096 x 1024, K=2048), BM=64 -> 512 blocks
    gemm_bt<2, 4, ACT_NONE, false, true, float, bf16>
        <<<dim3(8, 64), blk, 0, stream>>>(
        buf1, D_INNER, outwb, D_INNER, buf2, D_MODEL, nullptr, x, D_MODEL, D_INNER,
        outwb, buf2, 1000);

    // hidden = gelu(x1 @ w1^T + b1)      (4096 x 4096, K=1024) -> buf0:buf1
    gemm_bt<4, 4, ACT_GELU, true, false, float, bf16>
        <<<dim3(32, 32), blk, 0, stream>>>(
        buf2, D_MODEL, w1b, D_MODEL, buf0, D_FFN, b1, nf, 0, D_MODEL,
        w1b, buf0, 1000);

    // out0 = x1 + hidden @ w2^T + b2     (4096 x 1024, K=4096), BM=64 -> 512 blocks
    gemm_bt<2, 4, ACT_NONE, true, true, bf16, float>
        <<<dim3(8, 64), blk, 0, stream>>>(
        buf0, D_FFN, W8, D_FFN, out0, D_MODEL, b2, buf2, D_MODEL, D_FFN,
        W8, out0, 1000);
}

// Round 10
// 512.211 us; speedup vs baseline: 11.9233x; 11.9233x over previous
//
#include <hip/hip_runtime.h>
#include <hip/hip_bf16.h>
#include <math.h>

using bf16 = __hip_bfloat16;

typedef __attribute__((ext_vector_type(8))) short short8;
typedef __attribute__((ext_vector_type(4))) short shortx4;
typedef __attribute__((ext_vector_type(4))) float floatx4;

#define D_MODEL 1024
#define D_STATE 16
#define D_FFN   4096
#define D_INNER 2048
#define DT_RANK 64
#define BSZ     2
#define SEQ     2048
#define MROWS   (BSZ*SEQ)   /* 4096 */
#define NCHUNK  16
#define CLEN    (SEQ/NCHUNK)   /* 128 */

static __device__ __forceinline__ float bf2f(bf16 v) { return __bfloat162float(v); }
static __device__ __forceinline__ short f2s(float f) {
    bf16 h = __float2bfloat16(f);
    return *reinterpret_cast<short*>(&h);
}
static __device__ __forceinline__ float sbf(short s) {
    union { short s; bf16 h; } u; u.s = s; return __bfloat162float(u.h);
}
static __device__ __forceinline__ float rd(const bf16* p)  { return bf2f(*p); }
static __device__ __forceinline__ float rd(const float* p) { return *p; }
static __device__ __forceinline__ void  wr(bf16* p, float v)  { *p = __float2bfloat16(v); }
static __device__ __forceinline__ void  wr(float* p, float v) { *p = v; }

// s_waitcnt immediate (gfx9 enc): lgkmcnt(0) only — vmcnt/expcnt no-wait.
#define WAIT_LGKM0 0xC07F

// ---------------------------------------------------------------------------
// GEMM: C[M,N] = act(A[M,K] @ W[N,K]^T + bias) (+ resid). bf16 in, f32 accum.
// Pipelined K-loop, manually 2x-unrolled: two STATICALLY-NAMED register sets
// (set0/set1) give prefetch distance 2 with zero dynamic register indexing
// (round-9 lesson: dynamic-indexed staging arrays spill to scratch -> 26x).
// Raw s_barrier (no vmcnt drain), swizzled LDS (bank-conflict-free).
// Tile = (IT*32) x (JT*32), 4 waves in 2x2. Epilogue: chunked LDS transpose.
// Optional second (W2,C2) for by >= mtiles; XCD band swizzle when gx%8==0.
// Requires K/32 even.
// ---------------------------------------------------------------------------
#define BK 32

enum { ACT_NONE = 0, ACT_GELU = 1, ACT_SOFTPLUS = 2 };

template<int IT, int JT, int ACT, bool HAS_BIAS, bool HAS_RES,
         typename TR, typename TC>
__global__ __launch_bounds__(256)
void gemm_bt(const bf16* __restrict__ A, int lda,
             const bf16* __restrict__ W, int ldw,
             TC* __restrict__ C, int ldc,
             const float* __restrict__ bias,
             const TR* __restrict__ resid, int ldr,
             int K,
             const bf16* __restrict__ W2, TC* __restrict__ C2, int mtiles)
{
    constexpr int BM = IT * 32, BN = JT * 32;
    constexpr int NGA = BM / 64;            // A 16-row groups staged per wave
    constexpr int NGB = BN / 64;
    constexpr int ABYTES = BM * BK * 2;
    constexpr int BBYTES = BN * BK * 2;
    constexpr int EBYTES = 16 * (BN + 4) * 4;
    constexpr int SBYTES = (ABYTES + BBYTES) > EBYTES ? (ABYTES + BBYTES) : EBYTES;

    __shared__ __align__(16) char smem[SBYTES];
    bf16*  As = (bf16*)smem;
    bf16*  Bs = (bf16*)(smem + ABYTES);
    float* Ct = (float*)smem;               // epilogue alias (after K-loop)

    const int tid  = threadIdx.x;
    const int lane = tid & 63;
    const int wid  = tid >> 6;
    const int wm   = wid >> 1;
    const int wn   = wid & 1;
    const int quad = lane >> 4;
    const int lrow = lane & 15;

    // XCD band swizzle (bijective; gx multiple of 8)
    int bx = blockIdx.x, by = blockIdx.y;
    const int gx = gridDim.x;
    if ((gx & 7) == 0) {
        int id = by * gx + bx;
        int bw = gx >> 3;
        int band = id & 7, s = id >> 3;
        bx = band * bw + (s % bw);
        by = s / bw;
    }
    if (by >= mtiles) { by -= mtiles; W = W2; C = C2; }

    const long m0 = (long)by * BM;
    const long n0 = (long)bx * BN;

    // register staging addresses
    const int rlg  = lane >> 2;                 // row within 16-row group
    const int kfo  = (lane & 3) * 8;            // coalesced col offset
    const int slot = (((lane & 3) ^ ((rlg >> 1) & 3))) * 8;   // swizzled LDS col

    const bf16* Ag[NGA]; int soA[NGA];
    const bf16* Wg[NGB]; int soB[NGB];
    #pragma unroll
    for (int g = 0; g < NGA; ++g) {
        const int grp = wid * NGA + g;
        Ag[g]  = A + (m0 + grp * 16 + rlg) * (long)lda + kfo;
        soA[g] = (grp * 16 + rlg) * 32 + slot;
    }
    #pragma unroll
    for (int g = 0; g < NGB; ++g) {
        const int grp = wid * NGB + g;
        Wg[g]  = W + (n0 + grp * 16 + rlg) * (long)ldw + kfo;
        soB[g] = (grp * 16 + rlg) * 32 + slot;
    }

    // fragment read col offset (matches store swizzle; 2-way banks = free)
    const int co = ((quad ^ ((lrow >> 1) & 3))) * 8;

    floatx4 acc[IT][JT] = {};

    auto compute = [&]() {
        short8 af[IT], bfv[JT];
        #pragma unroll
        for (int i = 0; i < IT; i++)
            af[i] = *(const short8*)(As + (wm * IT * 16 + i * 16 + lrow) * 32 + co);
        #pragma unroll
        for (int j = 0; j < JT; j++)
            bfv[j] = *(const short8*)(Bs + (wn * JT * 16 + j * 16 + lrow) * 32 + co);
        #pragma unroll
        for (int i = 0; i < IT; i++)
            #pragma unroll
            for (int j = 0; j < JT; j++)
                acc[i][j] = __builtin_amdgcn_mfma_f32_16x16x32_bf16(af[i], bfv[j], acc[i][j], 0, 0, 0);
    };

    // two statically-named register sets (no dynamic indexing -> no spill)
    short8 a0[NGA], b0[NGB], a1[NGA], b1[NGB];
    #pragma unroll
    for (int g = 0; g < NGA; ++g) a0[g] = *(const short8*)Ag[g];
    #pragma unroll
    for (int g = 0; g < NGB; ++g) b0[g] = *(const short8*)Wg[g];
    #pragma unroll
    for (int g = 0; g < NGA; ++g) a1[g] = *(const short8*)(Ag[g] + BK);
    #pragma unroll
    for (int g = 0; g < NGB; ++g) b1[g] = *(const short8*)(Wg[g] + BK);

    const int nit2 = K / (2 * BK);          // K/32 even for all our shapes
    for (int ii = 0; ii < nit2; ++ii) {
        // ---- phase 0: tile 2ii ----
        #pragma unroll
        for (int g = 0; g < NGA; ++g) *(short8*)(As + soA[g]) = a0[g];
        #pragma unroll
        for (int g = 0; g < NGB; ++g) *(short8*)(Bs + soB[g]) = b0[g];
        __builtin_amdgcn_s_waitcnt(WAIT_LGKM0);
        __builtin_amdgcn_s_barrier();
        if (ii + 1 < nit2) {                // distance-2 prefetch into set0
            const long ko = (long)(2 * ii + 2) * BK;
            #pragma unroll
            for (int g = 0; g < NGA; ++g) a0[g] = *(const short8*)(Ag[g] + ko);
            #pragma unroll
            for (int g = 0; g < NGB; ++g) b0[g] = *(const short8*)(Wg[g] + ko);
        }
        compute();
        __builtin_amdgcn_s_barrier();

        // ---- phase 1: tile 2ii+1 ----
        #pragma unroll
        for (int g = 0; g < NGA; ++g) *(short8*)(As + soA[g]) = a1[g];
        #pragma unroll
        for (int g = 0; g < NGB; ++g) *(short8*)(Bs + soB[g]) = b1[g];
        __builtin_amdgcn_s_waitcnt(WAIT_LGKM0);
        __builtin_amdgcn_s_barrier();
        if (ii + 1 < nit2) {                // distance-2 prefetch into set1
            const long ko = (long)(2 * ii + 3) * BK;
            #pragma unroll
            for (int g = 0; g < NGA; ++g) a1[g] = *(const short8*)(Ag[g] + ko);
            #pragma unroll
            for (int g = 0; g < NGB; ++g) b1[g] = *(const short8*)(Wg[g] + ko);
        }
        compute();
        __builtin_amdgcn_s_barrier();
    }

    // ---------------- epilogue ----------------
    // bias + activation in-register (C/D layout: row=quad*4+r, col=lrow)
    if (HAS_BIAS || ACT != ACT_NONE) {
        #pragma unroll
        for (int j = 0; j < JT; ++j) {
            const long col = n0 + wn * JT * 16 + j * 16 + lrow;
            const float bv = HAS_BIAS ? bias[col] : 0.0f;
            #pragma unroll
            for (int i = 0; i < IT; ++i)
                #pragma unroll
                for (int r = 0; r < 4; ++r) {
                    float v = acc[i][j][r] + bv;
                    if (ACT == ACT_GELU)     v = 0.5f * v * (1.0f + erff(v * 0.70710678118f));
                    if (ACT == ACT_SOFTPLUS) v = (v > 20.0f) ? v : log1pf(__expf(v));
                    acc[i][j][r] = v;
                }
        }
    }

    // chunked LDS transpose: 16 rows/chunk, padded f32 LDS, coalesced stores
    constexpr int LDCT = BN + 4;
    #pragma unroll
    for (int c = 0; c < BM / 16; ++c) {
        __builtin_amdgcn_s_barrier();
        #pragma unroll
        for (int i = 0; i < IT; ++i) {
            if (wm * IT + i == c) {
                #pragma unroll
                for (int j = 0; j < JT; ++j) {
                    const int cl = wn * JT * 16 + j * 16 + lrow;
                    #pragma unroll
                    for (int r = 0; r < 4; ++r)
                        Ct[(quad * 4 + r) * LDCT + cl] = acc[i][j][r];
                }
            }
        }
        __builtin_amdgcn_s_waitcnt(WAIT_LGKM0);
        __builtin_amdgcn_s_barrier();
        const long rowg0 = m0 + c * 16;
        #pragma unroll
        for (int p = 0; p < (16 * BN) / (256 * 4); ++p) {
            const int g   = p * 256 + tid;
            const int row = (g * 4) / BN;
            const int col = (g * 4) & (BN - 1);
            const long rowg = rowg0 + row;
            float4 v4 = *(const float4*)(Ct + row * LDCT + col);
            float vv[4] = { v4.x, v4.y, v4.z, v4.w };
            #pragma unroll
            for (int e = 0; e < 4; ++e) {
                float v = vv[e];
                if (HAS_RES) v += rd(resid + rowg * (long)ldr + n0 + col + e);
                wr(C + rowg * (long)ldc + n0 + col + e, v);
            }
        }
    }
}

// ---------------------------------------------------------------------------
// fused weight/input prep (f32 -> bf16), 8 elems/thread
// ---------------------------------------------------------------------------
static __device__ __forceinline__ void cvt8(const float* __restrict__ s,
                                            bf16* __restrict__ d, long i)
{
    float4 a = *((const float4*)s + i * 2);
    float4 b = *((const float4*)s + i * 2 + 1);
    short8 r;
    r[0] = f2s(a.x); r[1] = f2s(a.y); r[2] = f2s(a.z); r[3] = f2s(a.w);
    r[4] = f2s(b.x); r[5] = f2s(b.y); r[6] = f2s(b.z); r[7] = f2s(b.w);
    *(short8*)(d + i * 8) = r;
}

__global__ __launch_bounds__(256)
void prep1(const float* __restrict__ x, const float* __restrict__ inw,
           const float* __restrict__ dtw, const float* __restrict__ xprojw,
           bf16* __restrict__ xbf, bf16* __restrict__ inwb,
           bf16* __restrict__ dtwb, bf16* __restrict__ wpad)
{
    const int bid = blockIdx.x;
    const long t = threadIdx.x;
    if (bid < 2048)      cvt8(x,   xbf,  (long)bid * 256 + t);
    else if (bid < 4096) cvt8(inw, inwb, (long)(bid - 2048) * 256 + t);
    else if (bid < 4160) cvt8(dtw, dtwb, (long)(bid - 4096) * 256 + t);
    else {
        long i = (long)(bid - 4160) * 256 + t;   // 8-elem groups of wpad (128x2048)
        int row = (int)(i >> 8);
        int c8  = (int)(i & 255) * 8;
        short8 r = {0, 0, 0, 0, 0, 0, 0, 0};
        if (row < 96) {
            const float* s = xprojw + (long)row * 2048 + c8;
            float4 a = *(const float4*)s, b = *(const float4*)(s + 4);
            r[0] = f2s(a.x); r[1] = f2s(a.y); r[2] = f2s(a.z); r[3] = f2s(a.w);
            r[4] = f2s(b.x); r[5] = f2s(b.y); r[6] = f2s(b.z); r[7] = f2s(b.w);
        }
        *(short8*)(wpad + (long)row * 2048 + c8) = r;
    }
}

__global__ __launch_bounds__(256)
void prep2(const float* __restrict__ outw, const float* __restrict__ w1,
           const float* __restrict__ w2,
           bf16* __restrict__ outwb, bf16* __restrict__ w1b,
           bf16* __restrict__ w2b)
{
    const int bid = blockIdx.x;
    const long t = threadIdx.x;
    if (bid < 1024)      cvt8(outw, outwb, (long)bid * 256 + t);
    else if (bid < 3072) cvt8(w1, w1b, (long)(bid - 1024) * 256 + t);
    else                 cvt8(w2, w2b, (long)(bid - 3072) * 256 + t);
}

// ---------------------------------------------------------------------------
// depthwise causal conv (K=3) + bias + silu
// ---------------------------------------------------------------------------
__global__ __launch_bounds__(256)
void conv_silu(const bf16* __restrict__ xpre, const float* __restrict__ cw,
               const float* __restrict__ cb, bf16* __restrict__ xp)
{
    long i = (long)blockIdx.x * 256 + threadIdx.x;
    int  d  = (int)(i & (D_INNER - 1));
    long bl = i >> 11;
    long l  = bl & (SEQ - 1);

    float w0 = cw[d * 3 + 0];
    float w1 = cw[d * 3 + 1];
    float w2 = cw[d * 3 + 2];
    float acc = cb[d] + w2 * bf2f(xpre[i]);
    if (l >= 1) acc += w1 * bf2f(xpre[i - D_INNER]);
    if (l >= 2) acc += w0 * bf2f(xpre[i - 2 * D_INNER]);
    float s = acc / (1.0f + __expf(-acc));
    xp[i] = __float2bfloat16(s);
}

// ---------------------------------------------------------------------------
// Chunked SSM scan (verified rounds 4-9)
// ---------------------------------------------------------------------------
#define SROWS 16
#define SDB   64
#define SNB   (CLEN/SROWS)   /* 8 */

__global__ __launch_bounds__(256)
void scan_part(const bf16* __restrict__ dt, const bf16* __restrict__ xp,
               const bf16* __restrict__ dbc, const float* __restrict__ Alog,
               float* __restrict__ Pbuf, float* __restrict__ Qbuf)
{
    __shared__ float2 Ap[2][SROWS][SDB];   // (dt, dt*xp)
    __shared__ float  Bp[2][SROWS][16];

    const int tid  = threadIdx.x;
    const int c    = blockIdx.x & (NCHUNK - 1);
    const int dgrp = (blockIdx.x >> 4) & 31;
    const int b    = blockIdx.x >> 9;
    const int d0   = dgrp * SDB;
    const long row0 = (long)b * SEQ + (long)c * CLEN;

    const int sl  = tid >> 4;
    const int sq  = tid & 15;
    const int sd4 = sq * 4;

    const int nt = tid & 3;
    const int dl = tid >> 2;
    const int n0 = nt * 4;
    const int d  = d0 + dl;

    const float4 Av = *(const float4*)(Alog + d * 16 + n0);
    float Ad[4] = { -__expf(Av.x), -__expf(Av.y), -__expf(Av.z), -__expf(Av.w) };

    float rdt[4], rdx[4], rB;
    auto ldb = [&](int bb) {
        long row = row0 + bb * SROWS + sl;
        shortx4 dv = *(const shortx4*)(dt + row * D_INNER + d0 + sd4);
        shortx4 xv = *(const shortx4*)(xp + row * D_INNER + d0 + sd4);
        #pragma unroll
        for (int k = 0; k < 4; k++) {
            float f = sbf(dv[k]);
            rdt[k] = f;
            rdx[k] = f * sbf(xv[k]);
        }
        rB = bf2f(dbc[row * 128 + 64 + sq]);
    };
    auto stb = [&](int bb) {
        int s = bb & 1;
        #pragma unroll
        for (int k = 0; k < 4; k++)
            Ap[s][sl][sd4 + k] = make_float2(rdt[k], rdx[k]);
        Bp[s][sl][sq] = rB;
    };

    float h[4] = {0.f, 0.f, 0.f, 0.f};
    float sdt = 0.f;

    ldb(0); stb(0);
    for (int bb = 0; bb < SNB; bb++) {
        if (bb + 1 < SNB) ldb(bb + 1);
        __syncthreads();
        const int s = bb & 1;
        #pragma unroll
        for (int l = 0; l < SROWS; l++) {
            float2  a  = Ap[s][l][dl];
            floatx4 Bq = *(const floatx4*)&Bp[s][l][n0];
            sdt += a.x;
            #pragma unroll
            for (int k = 0; k < 4; k++)
                h[k] = __expf(a.x * Ad[k]) * h[k] + a.y * Bq[k];
        }
        if (bb + 1 < SNB) stb(bb + 1);
    }

    const long base = ((long)(b * NCHUNK + c) * D_INNER + d) * 16 + n0;
    floatx4 P = { __expf(Ad[0] * sdt), __expf(Ad[1] * sdt),
                  __expf(Ad[2] * sdt), __expf(Ad[3] * sdt) };
    floatx4 Q = { h[0], h[1], h[2], h[3] };
    *(floatx4*)(Pbuf + base) = P;
    *(floatx4*)(Qbuf + base) = Q;
}

__global__ __launch_bounds__(256)
void scan_combine(const float* __restrict__ Pbuf, float* __restrict__ Qbuf,
                  float* __restrict__ state)
{
    long i = (long)blockIdx.x * 256 + threadIdx.x;   // 65536 = (b,d,n)
    int  n = (int)(i & 15);
    int  d = (int)((i >> 4) & (D_INNER - 1));
    int  b = (int)(i >> 15);
    float h = 0.0f;
    #pragma unroll
    for (int c = 0; c < NCHUNK; c++) {
        const long idx = ((long)(b * NCHUNK + c) * D_INNER + d) * 16 + n;
        float P = Pbuf[idx], Q = Qbuf[idx];
        Qbuf[idx] = h;               // exclusive prefix = h_in for chunk c
        h = P * h + Q;
    }
    state[((long)b * D_INNER + d) * 16 + n] = h;
}

__global__ __launch_bounds__(256)
void scan_final(const bf16* __restrict__ dt, bf16* __restrict__ xp,
                const bf16* __restrict__ dbc, const float* __restrict__ Alog,
                const bf16* __restrict__ z, const float* __restrict__ Dp,
                const float* __restrict__ Qbuf)
{
    __shared__ float2 Ap [2][SROWS][SDB];   // (dt, dt*xp)
    __shared__ float2 BCp[2][SROWS][16];    // (B, C)
    __shared__ float2 GWp[2][SROWS][SDB];   // (g=silu(z), w=xp*Dp*g)

    const int tid  = threadIdx.x;
    const int c    = blockIdx.x & (NCHUNK - 1);
    const int dgrp = (blockIdx.x >> 4) & 31;
    const int b    = blockIdx.x >> 9;
    const int d0   = dgrp * SDB;
    const long row0 = (long)b * SEQ + (long)c * CLEN;

    const int sl  = tid >> 4;
    const int sq  = tid & 15;
    const int sd4 = sq * 4;

    const int nt = tid & 3;
    const int dl = tid >> 2;
    const int n0 = nt * 4;
    const int d  = d0 + dl;

    const float4 Av = *(const float4*)(Alog + d * 16 + n0);
    float Ad[4] = { -__expf(Av.x), -__expf(Av.y), -__expf(Av.z), -__expf(Av.w) };
    const float4 Dv = *(const float4*)(Dp + d0 + sd4);
    const float Dk[4] = { Dv.x, Dv.y, Dv.z, Dv.w };

    float rdt[4], rdx[4], rg[4], rw[4], rB, rC;
    auto ldb = [&](int bb) {
        long row = row0 + bb * SROWS + sl;
        shortx4 dv = *(const shortx4*)(dt + row * D_INNER + d0 + sd4);
        shortx4 xv = *(const shortx4*)(xp + row * D_INNER + d0 + sd4);
        shortx4 zv = *(const shortx4*)(z  + row * D_INNER + d0 + sd4);
        #pragma unroll
        for (int k = 0; k < 4; k++) {
            float f  = sbf(dv[k]);
            float xf = sbf(xv[k]);
            float zf = sbf(zv[k]);
            float g  = zf / (1.0f + __expf(-zf));
            rdt[k] = f;
            rdx[k] = f * xf;
            rg[k]  = g;
            rw[k]  = xf * Dk[k] * g;
        }
        rB = bf2f(dbc[row * 128 + 64 + sq]);
        rC = bf2f(dbc[row * 128 + 80 + sq]);
    };
    auto stb = [&](int bb) {
        int s = bb & 1;
        #pragma unroll
        for (int k = 0; k < 4; k++) {
            Ap [s][sl][sd4 + k] = make_float2(rdt[k], rdx[k]);
            GWp[s][sl][sd4 + k] = make_float2(rg[k], rw[k]);
        }
        BCp[s][sl][sq] = make_float2(rB, rC);
    };

    float h[4];
    {
        const long base = ((long)(b * NCHUNK + c) * D_INNER + d) * 16 + n0;
        floatx4 q = *(const floatx4*)(Qbuf + base);
        h[0] = q[0]; h[1] = q[1]; h[2] = q[2]; h[3] = q[3];
    }

    ldb(0); stb(0);
    for (int bb = 0; bb < SNB; bb++) {
        if (bb + 1 < SNB) ldb(bb + 1);
        __syncthreads();
        const int s = bb & 1;
        #pragma unroll
        for (int l = 0; l < SROWS; l++) {
            float2  a   = Ap[s][l][dl];
            floatx4 bc0 = *(const floatx4*)&BCp[s][l][n0];      // B0,C0,B1,C1
            floatx4 bc1 = *(const floatx4*)&BCp[s][l][n0 + 2];  // B2,C2,B3,C3
            float yv;
            h[0] = __expf(a.x * Ad[0]) * h[0] + a.y * bc0[0];
            yv   = h[0] * bc0[1];
            h[1] = __expf(a.x * Ad[1]) * h[1] + a.y * bc0[2];
            yv  += h[1] * bc0[3];
            h[2] = __expf(a.x * Ad[2]) * h[2] + a.y * bc1[0];
            yv  += h[2] * bc1[1];
            h[3] = __expf(a.x * Ad[3]) * h[3] + a.y * bc1[2];
            yv  += h[3] * bc1[3];
            yv += __shfl_xor(yv, 1);
            yv += __shfl_xor(yv, 2);
            if (nt == 0) {
                float2 gw = GWp[s][l][dl];
                float out = yv * gw.x + gw.y;
                xp[(row0 + bb * SROWS + l) * (long)D_INNER + d0 + dl] =
                    __float2bfloat16(out);
            }
        }
        if (bb + 1 < SNB) stb(bb + 1);
    }
}

// ---------------------------------------------------------------------------
extern "C" void kernel_launch(void* const* d_in, const int* in_sizes, int n_in,
                              void* d_out, int out_size, void* d_ws, size_t ws_size,
                              hipStream_t stream)
{
    const float* x      = (const float*)d_in[0];
    const float* inw    = (const float*)d_in[1];
    const float* convw  = (const float*)d_in[2];
    const float* convb  = (const float*)d_in[3];
    const float* xprojw = (const float*)d_in[4];
    const float* dtw    = (const float*)d_in[5];
    const float* dtbias = (const float*)d_in[6];
    const float* Alog   = (const float*)d_in[7];
    const float* Dp     = (const float*)d_in[8];
    const float* outw   = (const float*)d_in[9];
    const float* w1     = (const float*)d_in[10];
    const float* b1     = (const float*)d_in[11];
    const float* w2     = (const float*)d_in[12];
    const float* b2     = (const float*)d_in[13];

    float* out0 = (float*)d_out;                     // (2,2048,1024) f32 @ [0,16MiB)
    float* out1 = out0 + (long)MROWS * D_MODEL;      // (2,2048,16)   f32 @ [16,16.25MiB)

    // ws (57.5 MiB, proven): 3 act bufs + dbc + wpad + W8 (inw -> w2)
    bf16* buf0 = (bf16*)d_ws;                        // xpre -> dt -> hidden lo
    bf16* buf1 = buf0 + (long)MROWS * D_INNER;       // xp -> gated y (in-place) -> hidden hi
    bf16* buf2 = buf1 + (long)MROWS * D_INNER;       // z -> x1
    bf16* dbc  = buf2 + (long)MROWS * D_INNER;       // (4096,128), 96 cols used
    bf16* wpad = dbc  + (long)MROWS * 128;           // (128,2048)
    bf16* W8   = wpad + 128 * 2048;                  // 8 MiB: inw (prep1) -> w2 (prep2)

    // d_out scratch overlays (each dead before its region is clobbered):
    bf16*  dtwb  = (bf16*)d_out;                               // [0,0.25M) prep1->dtGEMM; clobbered by Pbuf
    float* Pbuf  = (float*)d_out;                              // [0,4M)  scan
    float* Qbuf  = Pbuf + (long)BSZ * NCHUNK * D_INNER * 16;   // [4,8M)  scan
    bf16*  xbf   = (bf16*)((char*)d_out + 8 * 1024 * 1024);    // [8,16M) prep1->in_proj
    bf16*  w1b   = (bf16*)d_out;                               // [0,8M)  prep2->FFN1 (P/Q dead)
    bf16*  outwb = (bf16*)((char*)d_out + 8 * 1024 * 1024);    // [8,12M) prep2->out_proj (xbf dead)

    dim3 blk(256);
    const float* nf = nullptr;

    // prep1: x->xbf, inw->W8, dtw->dtwb, xprojw->wpad   (one dispatch)
    prep1<<<dim3(4288), blk, 0, stream>>>(x, inw, dtw, xprojw, xbf, W8, dtwb, wpad);

    // fused in_proj: xpre = x@inw_lo^T -> buf0 ; z = x@inw_hi^T -> buf2
    gemm_bt<4, 4, ACT_NONE, false, false, float, bf16>
        <<<dim3(16, 64), blk, 0, stream>>>(
        xbf, D_MODEL, W8, D_MODEL, buf0, D_INNER, nullptr, nf, 0, D_MODEL,
        W8 + (long)D_INNER * D_MODEL, buf2, 32);

    // xp = silu(causal_conv(xpre) + conv_b)
    conv_silu<<<dim3(32768), blk, 0, stream>>>(buf0, convw, convb, buf1);

    // dbc = xp @ x_proj_w^T              (4096 x 128pad, K=2048), BM=64 tile
    gemm_bt<2, 4, ACT_NONE, false, false, float, bf16>
        <<<dim3(1, 64), blk, 0, stream>>>(
        buf1, D_INNER, wpad, D_INNER, dbc, 128, nullptr, nf, 0, D_INNER,
        wpad, dbc, 1000);

    // dt = softplus(dbc[:, :64] @ dt_proj_w^T + dt_proj_b)   (4096 x 2048, K=64)
    gemm_bt<4, 4, ACT_SOFTPLUS, true, false, float, bf16>
        <<<dim3(16, 32), blk, 0, stream>>>(
        dbc, 128, dtwb, DT_RANK, buf0, D_INNER, dtbias, nf, 0, DT_RANK,
        dtwb, buf0, 1000);

    // chunked scan: phase1 -> combine (writes state) -> phase3 (gated y in buf1)
    scan_part<<<dim3(BSZ * NCHUNK * (D_INNER / SDB)), blk, 0, stream>>>(
        buf0, buf1, dbc, Alog, Pbuf, Qbuf);
    scan_combine<<<dim3(256), blk, 0, stream>>>(Pbuf, Qbuf, out1);
    scan_final<<<dim3(BSZ * NCHUNK * (D_INNER / SDB)), blk, 0, stream>>>(
        buf0, buf1, dbc, Alog, buf2, Dp, Qbuf);

    // prep2: outw->outwb, w1->w1b, w2->W8   (one dispatch; P/Q + xbf dead)
    prep2<<<dim3(5120), blk, 0, stream>>>(outw, w1, w2, outwb, w1b, W8);

    // x1 = x + y @ out_proj_w^T          (4096 x 1024, K=2048), BM=64 -> 512 blocks
    gemm_bt<2, 4, ACT_NONE, false, true, float, bf16>
        <<<dim3(8, 64), blk, 0, stream>>>(
        buf1, D_INNER, outwb, D_INNER, buf2, D_MODEL, nullptr, x, D_MODEL, D_INNER,
        outwb, buf2, 1000);

    // hidden = gelu(x1 @ w1^T + b1)      (4096 x 4096, K=1024) -> buf0:buf1
    gemm_bt<4, 4, ACT_GELU, true, false, float, bf16>
        <<<dim3(32, 32), blk, 0, stream>>>(
        buf2, D_MODEL, w1b, D_MODEL, buf0, D_FFN, b1, nf, 0, D_MODEL,
        w1b, buf0, 1000);

    // out0 = x1 + hidden @ w2^T + b2     (4096 x 1024, K=4096), BM=64 -> 512 blocks
    gemm_bt<2, 4, ACT_NONE, true, true, bf16, float>
        <<<dim3(8, 64), blk, 0, stream>>>(
        buf0, D_FFN, W8, D_FFN, out0, D_MODEL, b2, buf2, D_MODEL, D_FFN,
        W8, out0, 1000);
}

// Round 11
// 509.755 us; speedup vs baseline: 11.9807x; 1.0048x over previous
//
#include <hip/hip_runtime.h>
#include <hip/hip_bf16.h>
#include <math.h>

using bf16 = __hip_bfloat16;

typedef __attribute__((ext_vector_type(8))) short short8;
typedef __attribute__((ext_vector_type(4))) short shortx4;
typedef __attribute__((ext_vector_type(4))) float floatx4;

#define D_MODEL 1024
#define D_STATE 16
#define D_FFN   4096
#define D_INNER 2048
#define DT_RANK 64
#define BSZ     2
#define SEQ     2048
#define MROWS   (BSZ*SEQ)   /* 4096 */
#define NCHUNK  16
#define CLEN    (SEQ/NCHUNK)   /* 128 */

static __device__ __forceinline__ float bf2f(bf16 v) { return __bfloat162float(v); }
static __device__ __forceinline__ short f2s(float f) {
    bf16 h = __float2bfloat16(f);
    return *reinterpret_cast<short*>(&h);
}
static __device__ __forceinline__ float sbf(short s) {
    union { short s; bf16 h; } u; u.s = s; return __bfloat162float(u.h);
}
static __device__ __forceinline__ float rd(const bf16* p)  { return bf2f(*p); }
static __device__ __forceinline__ float rd(const float* p) { return *p; }

// s_waitcnt immediate (gfx9 enc): lgkmcnt(0) only — vmcnt/expcnt no-wait.
#define WAIT_LGKM0 0xC07F

// ---------------------------------------------------------------------------
// GEMM: C[M,N] = act(A[M,K] @ W[N,K]^T + bias) (+ resid). bf16 in, f32 accum.
// Pipelined K-loop, manually 2x-unrolled, two statically-named register sets
// (distance-2 prefetch, no dynamic indexing -> no spill). Raw s_barrier (no
// vmcnt drain), swizzled LDS. __launch_bounds__(256,4) caps VGPR at 128 —
// round-10 lesson: 132 VGPR put us over the 128 cliff (2 waves/SIMD only).
// Epilogue: chunked LDS transpose + vectorized (short4/float4) stores.
// ---------------------------------------------------------------------------
#define BK 32

enum { ACT_NONE = 0, ACT_GELU = 1, ACT_SOFTPLUS = 2 };

template<int IT, int JT, int ACT, bool HAS_BIAS, bool HAS_RES,
         typename TR, typename TC>
__global__ __launch_bounds__(256, 4)
void gemm_bt(const bf16* __restrict__ A, int lda,
             const bf16* __restrict__ W, int ldw,
             TC* __restrict__ C, int ldc,
             const float* __restrict__ bias,
             const TR* __restrict__ resid, int ldr,
             int K,
             const bf16* __restrict__ W2, TC* __restrict__ C2, int mtiles)
{
    constexpr int BM = IT * 32, BN = JT * 32;
    constexpr int NGA = BM / 64;            // A 16-row groups staged per wave
    constexpr int NGB = BN / 64;
    constexpr int ABYTES = BM * BK * 2;
    constexpr int BBYTES = BN * BK * 2;
    constexpr int EBYTES = 16 * (BN + 4) * 4;
    constexpr int SBYTES = (ABYTES + BBYTES) > EBYTES ? (ABYTES + BBYTES) : EBYTES;

    __shared__ __align__(16) char smem[SBYTES];
    bf16*  As = (bf16*)smem;
    bf16*  Bs = (bf16*)(smem + ABYTES);
    float* Ct = (float*)smem;               // epilogue alias (after K-loop)

    const int tid  = threadIdx.x;
    const int lane = tid & 63;
    const int wid  = tid >> 6;
    const int wm   = wid >> 1;
    const int wn   = wid & 1;
    const int quad = lane >> 4;
    const int lrow = lane & 15;

    // XCD band swizzle (bijective; gx multiple of 8)
    int bx = blockIdx.x, by = blockIdx.y;
    const int gx = gridDim.x;
    if ((gx & 7) == 0) {
        int id = by * gx + bx;
        int bw = gx >> 3;
        int band = id & 7, s = id >> 3;
        bx = band * bw + (s % bw);
        by = s / bw;
    }
    if (by >= mtiles) { by -= mtiles; W = W2; C = C2; }

    const long m0 = (long)by * BM;
    const long n0 = (long)bx * BN;

    // register staging addresses
    const int rlg  = lane >> 2;                 // row within 16-row group
    const int kfo  = (lane & 3) * 8;            // coalesced col offset
    const int slot = (((lane & 3) ^ ((rlg >> 1) & 3))) * 8;   // swizzled LDS col

    const bf16* Ag[NGA]; int soA[NGA];
    const bf16* Wg[NGB]; int soB[NGB];
    #pragma unroll
    for (int g = 0; g < NGA; ++g) {
        const int grp = wid * NGA + g;
        Ag[g]  = A + (m0 + grp * 16 + rlg) * (long)lda + kfo;
        soA[g] = (grp * 16 + rlg) * 32 + slot;
    }
    #pragma unroll
    for (int g = 0; g < NGB; ++g) {
        const int grp = wid * NGB + g;
        Wg[g]  = W + (n0 + grp * 16 + rlg) * (long)ldw + kfo;
        soB[g] = (grp * 16 + rlg) * 32 + slot;
    }

    // fragment read col offset (matches store swizzle; 2-way banks = free)
    const int co = ((quad ^ ((lrow >> 1) & 3))) * 8;

    floatx4 acc[IT][JT] = {};

    auto compute = [&]() {
        short8 af[IT], bfv[JT];
        #pragma unroll
        for (int i = 0; i < IT; i++)
            af[i] = *(const short8*)(As + (wm * IT * 16 + i * 16 + lrow) * 32 + co);
        #pragma unroll
        for (int j = 0; j < JT; j++)
            bfv[j] = *(const short8*)(Bs + (wn * JT * 16 + j * 16 + lrow) * 32 + co);
        #pragma unroll
        for (int i = 0; i < IT; i++)
            #pragma unroll
            for (int j = 0; j < JT; j++)
                acc[i][j] = __builtin_amdgcn_mfma_f32_16x16x32_bf16(af[i], bfv[j], acc[i][j], 0, 0, 0);
    };

    // two statically-named register sets (no dynamic indexing -> no spill)
    short8 a0[NGA], b0[NGB], a1[NGA], b1[NGB];
    #pragma unroll
    for (int g = 0; g < NGA; ++g) a0[g] = *(const short8*)Ag[g];
    #pragma unroll
    for (int g = 0; g < NGB; ++g) b0[g] = *(const short8*)Wg[g];
    #pragma unroll
    for (int g = 0; g < NGA; ++g) a1[g] = *(const short8*)(Ag[g] + BK);
    #pragma unroll
    for (int g = 0; g < NGB; ++g) b1[g] = *(const short8*)(Wg[g] + BK);

    const int nit2 = K / (2 * BK);          // K/32 even for all our shapes
    for (int ii = 0; ii < nit2; ++ii) {
        // ---- phase 0: tile 2ii ----
        #pragma unroll
        for (int g = 0; g < NGA; ++g) *(short8*)(As + soA[g]) = a0[g];
        #pragma unroll
        for (int g = 0; g < NGB; ++g) *(short8*)(Bs + soB[g]) = b0[g];
        __builtin_amdgcn_s_waitcnt(WAIT_LGKM0);
        __builtin_amdgcn_s_barrier();
        if (ii + 1 < nit2) {                // distance-2 prefetch into set0
            const long ko = (long)(2 * ii + 2) * BK;
            #pragma unroll
            for (int g = 0; g < NGA; ++g) a0[g] = *(const short8*)(Ag[g] + ko);
            #pragma unroll
            for (int g = 0; g < NGB; ++g) b0[g] = *(const short8*)(Wg[g] + ko);
        }
        compute();
        __builtin_amdgcn_s_barrier();

        // ---- phase 1: tile 2ii+1 ----
        #pragma unroll
        for (int g = 0; g < NGA; ++g) *(short8*)(As + soA[g]) = a1[g];
        #pragma unroll
        for (int g = 0; g < NGB; ++g) *(short8*)(Bs + soB[g]) = b1[g];
        __builtin_amdgcn_s_waitcnt(WAIT_LGKM0);
        __builtin_amdgcn_s_barrier();
        if (ii + 1 < nit2) {                // distance-2 prefetch into set1
            const long ko = (long)(2 * ii + 3) * BK;
            #pragma unroll
            for (int g = 0; g < NGA; ++g) a1[g] = *(const short8*)(Ag[g] + ko);
            #pragma unroll
            for (int g = 0; g < NGB; ++g) b1[g] = *(const short8*)(Wg[g] + ko);
        }
        compute();
        __builtin_amdgcn_s_barrier();
    }

    // ---------------- epilogue ----------------
    // bias + activation in-register (C/D layout: row=quad*4+r, col=lrow)
    if (HAS_BIAS || ACT != ACT_NONE) {
        #pragma unroll
        for (int j = 0; j < JT; ++j) {
            const long col = n0 + wn * JT * 16 + j * 16 + lrow;
            const float bv = HAS_BIAS ? bias[col] : 0.0f;
            #pragma unroll
            for (int i = 0; i < IT; ++i)
                #pragma unroll
                for (int r = 0; r < 4; ++r) {
                    float v = acc[i][j][r] + bv;
                    if (ACT == ACT_GELU)     v = 0.5f * v * (1.0f + erff(v * 0.70710678118f));
                    if (ACT == ACT_SOFTPLUS) v = (v > 20.0f) ? v : log1pf(__expf(v));
                    acc[i][j][r] = v;
                }
        }
    }

    // chunked LDS transpose: 16 rows/chunk, padded f32 LDS, vectorized stores
    constexpr int LDCT = BN + 4;
    #pragma unroll
    for (int c = 0; c < BM / 16; ++c) {
        __builtin_amdgcn_s_barrier();
        #pragma unroll
        for (int i = 0; i < IT; ++i) {
            if (wm * IT + i == c) {
                #pragma unroll
                for (int j = 0; j < JT; ++j) {
                    const int cl = wn * JT * 16 + j * 16 + lrow;
                    #pragma unroll
                    for (int r = 0; r < 4; ++r)
                        Ct[(quad * 4 + r) * LDCT + cl] = acc[i][j][r];
                }
            }
        }
        __builtin_amdgcn_s_waitcnt(WAIT_LGKM0);
        __builtin_amdgcn_s_barrier();
        const long rowg0 = m0 + c * 16;
        #pragma unroll
        for (int p = 0; p < (16 * BN) / (256 * 4); ++p) {
            const int g   = p * 256 + tid;
            const int row = (g * 4) / BN;
            const int col = (g * 4) & (BN - 1);
            const long rowg = rowg0 + row;
            float4 v4 = *(const float4*)(Ct + row * LDCT + col);
            float vv[4] = { v4.x, v4.y, v4.z, v4.w };
            if (HAS_RES) {
                #pragma unroll
                for (int e = 0; e < 4; ++e)
                    vv[e] += rd(resid + rowg * (long)ldr + n0 + col + e);
            }
            if (sizeof(TC) == 2) {          // bf16: one 8-byte store
                shortx4 pk;
                #pragma unroll
                for (int e = 0; e < 4; ++e) pk[e] = f2s(vv[e]);
                *(shortx4*)((bf16*)C + rowg * (long)ldc + n0 + col) = pk;
            } else {                        // f32: one 16-byte store
                floatx4 pk = { vv[0], vv[1], vv[2], vv[3] };
                *(floatx4*)((float*)C + rowg * (long)ldc + n0 + col) = pk;
            }
        }
    }
}

// ---------------------------------------------------------------------------
// fused weight/input prep (f32 -> bf16), 8 elems/thread
// ---------------------------------------------------------------------------
static __device__ __forceinline__ void cvt8(const float* __restrict__ s,
                                            bf16* __restrict__ d, long i)
{
    float4 a = *((const float4*)s + i * 2);
    float4 b = *((const float4*)s + i * 2 + 1);
    short8 r;
    r[0] = f2s(a.x); r[1] = f2s(a.y); r[2] = f2s(a.z); r[3] = f2s(a.w);
    r[4] = f2s(b.x); r[5] = f2s(b.y); r[6] = f2s(b.z); r[7] = f2s(b.w);
    *(short8*)(d + i * 8) = r;
}

__global__ __launch_bounds__(256)
void prep1(const float* __restrict__ x, const float* __restrict__ inw,
           const float* __restrict__ dtw, const float* __restrict__ xprojw,
           bf16* __restrict__ xbf, bf16* __restrict__ inwb,
           bf16* __restrict__ dtwb, bf16* __restrict__ wpad)
{
    const int bid = blockIdx.x;
    const long t = threadIdx.x;
    if (bid < 2048)      cvt8(x,   xbf,  (long)bid * 256 + t);
    else if (bid < 4096) cvt8(inw, inwb, (long)(bid - 2048) * 256 + t);
    else if (bid < 4160) cvt8(dtw, dtwb, (long)(bid - 4096) * 256 + t);
    else {
        long i = (long)(bid - 4160) * 256 + t;   // 8-elem groups of wpad (128x2048)
        int row = (int)(i >> 8);
        int c8  = (int)(i & 255) * 8;
        short8 r = {0, 0, 0, 0, 0, 0, 0, 0};
        if (row < 96) {
            const float* s = xprojw + (long)row * 2048 + c8;
            float4 a = *(const float4*)s, b = *(const float4*)(s + 4);
            r[0] = f2s(a.x); r[1] = f2s(a.y); r[2] = f2s(a.z); r[3] = f2s(a.w);
            r[4] = f2s(b.x); r[5] = f2s(b.y); r[6] = f2s(b.z); r[7] = f2s(b.w);
        }
        *(short8*)(wpad + (long)row * 2048 + c8) = r;
    }
}

__global__ __launch_bounds__(256)
void prep2(const float* __restrict__ outw, const float* __restrict__ w1,
           const float* __restrict__ w2,
           bf16* __restrict__ outwb, bf16* __restrict__ w1b,
           bf16* __restrict__ w2b)
{
    const int bid = blockIdx.x;
    const long t = threadIdx.x;
    if (bid < 1024)      cvt8(outw, outwb, (long)bid * 256 + t);
    else if (bid < 3072) cvt8(w1, w1b, (long)(bid - 1024) * 256 + t);
    else                 cvt8(w2, w2b, (long)(bid - 3072) * 256 + t);
}

// ---------------------------------------------------------------------------
// depthwise causal conv (K=3) + bias + silu
// ---------------------------------------------------------------------------
__global__ __launch_bounds__(256)
void conv_silu(const bf16* __restrict__ xpre, const float* __restrict__ cw,
               const float* __restrict__ cb, bf16* __restrict__ xp)
{
    long i = (long)blockIdx.x * 256 + threadIdx.x;
    int  d  = (int)(i & (D_INNER - 1));
    long bl = i >> 11;
    long l  = bl & (SEQ - 1);

    float w0 = cw[d * 3 + 0];
    float w1 = cw[d * 3 + 1];
    float w2 = cw[d * 3 + 2];
    float acc = cb[d] + w2 * bf2f(xpre[i]);
    if (l >= 1) acc += w1 * bf2f(xpre[i - D_INNER]);
    if (l >= 2) acc += w0 * bf2f(xpre[i - 2 * D_INNER]);
    float s = acc / (1.0f + __expf(-acc));
    xp[i] = __float2bfloat16(s);
}

// ---------------------------------------------------------------------------
// Chunked SSM scan (verified rounds 4-10)
// ---------------------------------------------------------------------------
#define SROWS 16
#define SDB   64
#define SNB   (CLEN/SROWS)   /* 8 */

__global__ __launch_bounds__(256)
void scan_part(const bf16* __restrict__ dt, const bf16* __restrict__ xp,
               const bf16* __restrict__ dbc, const float* __restrict__ Alog,
               float* __restrict__ Pbuf, float* __restrict__ Qbuf)
{
    __shared__ float2 Ap[2][SROWS][SDB];   // (dt, dt*xp)
    __shared__ float  Bp[2][SROWS][16];

    const int tid  = threadIdx.x;
    const int c    = blockIdx.x & (NCHUNK - 1);
    const int dgrp = (blockIdx.x >> 4) & 31;
    const int b    = blockIdx.x >> 9;
    const int d0   = dgrp * SDB;
    const long row0 = (long)b * SEQ + (long)c * CLEN;

    const int sl  = tid >> 4;
    const int sq  = tid & 15;
    const int sd4 = sq * 4;

    const int nt = tid & 3;
    const int dl = tid >> 2;
    const int n0 = nt * 4;
    const int d  = d0 + dl;

    const float4 Av = *(const float4*)(Alog + d * 16 + n0);
    float Ad[4] = { -__expf(Av.x), -__expf(Av.y), -__expf(Av.z), -__expf(Av.w) };

    float rdt[4], rdx[4], rB;
    auto ldb = [&](int bb) {
        long row = row0 + bb * SROWS + sl;
        shortx4 dv = *(const shortx4*)(dt + row * D_INNER + d0 + sd4);
        shortx4 xv = *(const shortx4*)(xp + row * D_INNER + d0 + sd4);
        #pragma unroll
        for (int k = 0; k < 4; k++) {
            float f = sbf(dv[k]);
            rdt[k] = f;
            rdx[k] = f * sbf(xv[k]);
        }
        rB = bf2f(dbc[row * 128 + 64 + sq]);
    };
    auto stb = [&](int bb) {
        int s = bb & 1;
        #pragma unroll
        for (int k = 0; k < 4; k++)
            Ap[s][sl][sd4 + k] = make_float2(rdt[k], rdx[k]);
        Bp[s][sl][sq] = rB;
    };

    float h[4] = {0.f, 0.f, 0.f, 0.f};
    float sdt = 0.f;

    ldb(0); stb(0);
    for (int bb = 0; bb < SNB; bb++) {
        if (bb + 1 < SNB) ldb(bb + 1);
        __syncthreads();
        const int s = bb & 1;
        #pragma unroll
        for (int l = 0; l < SROWS; l++) {
            float2  a  = Ap[s][l][dl];
            floatx4 Bq = *(const floatx4*)&Bp[s][l][n0];
            sdt += a.x;
            #pragma unroll
            for (int k = 0; k < 4; k++)
                h[k] = __expf(a.x * Ad[k]) * h[k] + a.y * Bq[k];
        }
        if (bb + 1 < SNB) stb(bb + 1);
    }

    const long base = ((long)(b * NCHUNK + c) * D_INNER + d) * 16 + n0;
    floatx4 P = { __expf(Ad[0] * sdt), __expf(Ad[1] * sdt),
                  __expf(Ad[2] * sdt), __expf(Ad[3] * sdt) };
    floatx4 Q = { h[0], h[1], h[2], h[3] };
    *(floatx4*)(Pbuf + base) = P;
    *(floatx4*)(Qbuf + base) = Q;
}

__global__ __launch_bounds__(256)
void scan_combine(const float* __restrict__ Pbuf, float* __restrict__ Qbuf,
                  float* __restrict__ state)
{
    long i = (long)blockIdx.x * 256 + threadIdx.x;   // 65536 = (b,d,n)
    int  n = (int)(i & 15);
    int  d = (int)((i >> 4) & (D_INNER - 1));
    int  b = (int)(i >> 15);
    float h = 0.0f;
    #pragma unroll
    for (int c = 0; c < NCHUNK; c++) {
        const long idx = ((long)(b * NCHUNK + c) * D_INNER + d) * 16 + n;
        float P = Pbuf[idx], Q = Qbuf[idx];
        Qbuf[idx] = h;               // exclusive prefix = h_in for chunk c
        h = P * h + Q;
    }
    state[((long)b * D_INNER + d) * 16 + n] = h;
}

__global__ __launch_bounds__(256)
void scan_final(const bf16* __restrict__ dt, bf16* __restrict__ xp,
                const bf16* __restrict__ dbc, const float* __restrict__ Alog,
                const bf16* __restrict__ z, const float* __restrict__ Dp,
                const float* __restrict__ Qbuf)
{
    __shared__ float2 Ap [2][SROWS][SDB];   // (dt, dt*xp)
    __shared__ float2 BCp[2][SROWS][16];    // (B, C)
    __shared__ float2 GWp[2][SROWS][SDB];   // (g=silu(z), w=xp*Dp*g)

    const int tid  = threadIdx.x;
    const int c    = blockIdx.x & (NCHUNK - 1);
    const int dgrp = (blockIdx.x >> 4) & 31;
    const int b    = blockIdx.x >> 9;
    const int d0   = dgrp * SDB;
    const long row0 = (long)b * SEQ + (long)c * CLEN;

    const int sl  = tid >> 4;
    const int sq  = tid & 15;
    const int sd4 = sq * 4;

    const int nt = tid & 3;
    const int dl = tid >> 2;
    const int n0 = nt * 4;
    const int d  = d0 + dl;

    const float4 Av = *(const float4*)(Alog + d * 16 + n0);
    float Ad[4] = { -__expf(Av.x), -__expf(Av.y), -__expf(Av.z), -__expf(Av.w) };
    const float4 Dv = *(const float4*)(Dp + d0 + sd4);
    const float Dk[4] = { Dv.x, Dv.y, Dv.z, Dv.w };

    float rdt[4], rdx[4], rg[4], rw[4], rB, rC;
    auto ldb = [&](int bb) {
        long row = row0 + bb * SROWS + sl;
        shortx4 dv = *(const shortx4*)(dt + row * D_INNER + d0 + sd4);
        shortx4 xv = *(const shortx4*)(xp + row * D_INNER + d0 + sd4);
        shortx4 zv = *(const shortx4*)(z  + row * D_INNER + d0 + sd4);
        #pragma unroll
        for (int k = 0; k < 4; k++) {
            float f  = sbf(dv[k]);
            float xf = sbf(xv[k]);
            float zf = sbf(zv[k]);
            float g  = zf / (1.0f + __expf(-zf));
            rdt[k] = f;
            rdx[k] = f * xf;
            rg[k]  = g;
            rw[k]  = xf * Dk[k] * g;
        }
        rB = bf2f(dbc[row * 128 + 64 + sq]);
        rC = bf2f(dbc[row * 128 + 80 + sq]);
    };
    auto stb = [&](int bb) {
        int s = bb & 1;
        #pragma unroll
        for (int k = 0; k < 4; k++) {
            Ap [s][sl][sd4 + k] = make_float2(rdt[k], rdx[k]);
            GWp[s][sl][sd4 + k] = make_float2(rg[k], rw[k]);
        }
        BCp[s][sl][sq] = make_float2(rB, rC);
    };

    float h[4];
    {
        const long base = ((long)(b * NCHUNK + c) * D_INNER + d) * 16 + n0;
        floatx4 q = *(const floatx4*)(Qbuf + base);
        h[0] = q[0]; h[1] = q[1]; h[2] = q[2]; h[3] = q[3];
    }

    ldb(0); stb(0);
    for (int bb = 0; bb < SNB; bb++) {
        if (bb + 1 < SNB) ldb(bb + 1);
        __syncthreads();
        const int s = bb & 1;
        #pragma unroll
        for (int l = 0; l < SROWS; l++) {
            float2  a   = Ap[s][l][dl];
            floatx4 bc0 = *(const floatx4*)&BCp[s][l][n0];      // B0,C0,B1,C1
            floatx4 bc1 = *(const floatx4*)&BCp[s][l][n0 + 2];  // B2,C2,B3,C3
            float yv;
            h[0] = __expf(a.x * Ad[0]) * h[0] + a.y * bc0[0];
            yv   = h[0] * bc0[1];
            h[1] = __expf(a.x * Ad[1]) * h[1] + a.y * bc0[2];
            yv  += h[1] * bc0[3];
            h[2] = __expf(a.x * Ad[2]) * h[2] + a.y * bc1[0];
            yv  += h[2] * bc1[1];
            h[3] = __expf(a.x * Ad[3]) * h[3] + a.y * bc1[2];
            yv  += h[3] * bc1[3];
            yv += __shfl_xor(yv, 1);
            yv += __shfl_xor(yv, 2);
            if (nt == 0) {
                float2 gw = GWp[s][l][dl];
                float out = yv * gw.x + gw.y;
                xp[(row0 + bb * SROWS + l) * (long)D_INNER + d0 + dl] =
                    __float2bfloat16(out);
            }
        }
        if (bb + 1 < SNB) stb(bb + 1);
    }
}

// ---------------------------------------------------------------------------
extern "C" void kernel_launch(void* const* d_in, const int* in_sizes, int n_in,
                              void* d_out, int out_size, void* d_ws, size_t ws_size,
                              hipStream_t stream)
{
    const float* x      = (const float*)d_in[0];
    const float* inw    = (const float*)d_in[1];
    const float* convw  = (const float*)d_in[2];
    const float* convb  = (const float*)d_in[3];
    const float* xprojw = (const float*)d_in[4];
    const float* dtw    = (const float*)d_in[5];
    const float* dtbias = (const float*)d_in[6];
    const float* Alog   = (const float*)d_in[7];
    const float* Dp     = (const float*)d_in[8];
    const float* outw   = (const float*)d_in[9];
    const float* w1     = (const float*)d_in[10];
    const float* b1     = (const float*)d_in[11];
    const float* w2     = (const float*)d_in[12];
    const float* b2     = (const float*)d_in[13];

    float* out0 = (float*)d_out;                     // (2,2048,1024) f32 @ [0,16MiB)
    float* out1 = out0 + (long)MROWS * D_MODEL;      // (2,2048,16)   f32 @ [16,16.25MiB)

    // ws (57.5 MiB, proven): 3 act bufs + dbc + wpad + W8 (inw -> w2)
    bf16* buf0 = (bf16*)d_ws;                        // xpre -> dt -> hidden lo
    bf16* buf1 = buf0 + (long)MROWS * D_INNER;       // xp -> gated y (in-place) -> hidden hi
    bf16* buf2 = buf1 + (long)MROWS * D_INNER;       // z -> x1
    bf16* dbc  = buf2 + (long)MROWS * D_INNER;       // (4096,128), 96 cols used
    bf16* wpad = dbc  + (long)MROWS * 128;           // (128,2048)
    bf16* W8   = wpad + 128 * 2048;                  // 8 MiB: inw (prep1) -> w2 (prep2)

    // d_out scratch overlays (each dead before its region is clobbered):
    bf16*  dtwb  = (bf16*)d_out;                               // [0,0.25M) prep1->dtGEMM; clobbered by Pbuf
    float* Pbuf  = (float*)d_out;                              // [0,4M)  scan
    float* Qbuf  = Pbuf + (long)BSZ * NCHUNK * D_INNER * 16;   // [4,8M)  scan
    bf16*  xbf   = (bf16*)((char*)d_out + 8 * 1024 * 1024);    // [8,16M) prep1->in_proj
    bf16*  w1b   = (bf16*)d_out;                               // [0,8M)  prep2->FFN1 (P/Q dead)
    bf16*  outwb = (bf16*)((char*)d_out + 8 * 1024 * 1024);    // [8,12M) prep2->out_proj (xbf dead)

    dim3 blk(256);
    const float* nf = nullptr;

    // prep1: x->xbf, inw->W8, dtw->dtwb, xprojw->wpad   (one dispatch)
    prep1<<<dim3(4288), blk, 0, stream>>>(x, inw, dtw, xprojw, xbf, W8, dtwb, wpad);

    // fused in_proj: xpre = x@inw_lo^T -> buf0 ; z = x@inw_hi^T -> buf2
    gemm_bt<4, 4, ACT_NONE, false, false, float, bf16>
        <<<dim3(16, 64), blk, 0, stream>>>(
        xbf, D_MODEL, W8, D_MODEL, buf0, D_INNER, nullptr, nf, 0, D_MODEL,
        W8 + (long)D_INNER * D_MODEL, buf2, 32);

    // xp = silu(causal_conv(xpre) + conv_b)
    conv_silu<<<dim3(32768), blk, 0, stream>>>(buf0, convw, convb, buf1);

    // dbc = xp @ x_proj_w^T              (4096 x 128pad, K=2048), BM=64 tile
    gemm_bt<2, 4, ACT_NONE, false, false, float, bf16>
        <<<dim3(1, 64), blk, 0, stream>>>(
        buf1, D_INNER, wpad, D_INNER, dbc, 128, nullptr, nf, 0, D_INNER,
        wpad, dbc, 1000);

    // dt = softplus(dbc[:, :64] @ dt_proj_w^T + dt_proj_b)   (4096 x 2048, K=64)
    gemm_bt<4, 4, ACT_SOFTPLUS, true, false, float, bf16>
        <<<dim3(16, 32), blk, 0, stream>>>(
        dbc, 128, dtwb, DT_RANK, buf0, D_INNER, dtbias, nf, 0, DT_RANK,
        dtwb, buf0, 1000);

    // chunked scan: phase1 -> combine (writes state) -> phase3 (gated y in buf1)
    scan_part<<<dim3(BSZ * NCHUNK * (D_INNER / SDB)), blk, 0, stream>>>(
        buf0, buf1, dbc, Alog, Pbuf, Qbuf);
    scan_combine<<<dim3(256), blk, 0, stream>>>(Pbuf, Qbuf, out1);
    scan_final<<<dim3(BSZ * NCHUNK * (D_INNER / SDB)), blk, 0, stream>>>(
        buf0, buf1, dbc, Alog, buf2, Dp, Qbuf);

    // prep2: outw->outwb, w1->w1b, w2->W8   (one dispatch; P/Q + xbf dead)
    prep2<<<dim3(5120), blk, 0, stream>>>(outw, w1, w2, outwb, w1b, W8);

    // x1 = x + y @ out_proj_w^T          (4096 x 1024, K=2048), BM=64 -> 512 blocks
    gemm_bt<2, 4, ACT_NONE, false, true, float, bf16>
        <<<dim3(8, 64), blk, 0, stream>>>(
        buf1, D_INNER, outwb, D_INNER, buf2, D_MODEL, nullptr, x, D_MODEL, D_INNER,
        outwb, buf2, 1000);

    // hidden = gelu(x1 @ w1^T + b1)      (4096 x 4096, K=1024) -> buf0:buf1
    gemm_bt<4, 4, ACT_GELU, true, false, float, bf16>
        <<<dim3(32, 32), blk, 0, stream>>>(
        buf2, D_MODEL, w1b, D_MODEL, buf0, D_FFN, b1, nf, 0, D_MODEL,
        w1b, buf0, 1000);

    // out0 = x1 + hidden @ w2^T + b2     (4096 x 1024, K=4096), BM=64 -> 512 blocks
    gemm_bt<2, 4, ACT_NONE, true, true, bf16, float>
        <<<dim3(8, 64), blk, 0, stream>>>(
        buf0, D_FFN, W8, D_FFN, out0, D_MODEL, b2, buf2, D_MODEL, D_FFN,
        W8, out0, 1000);
}